// Round 4
// baseline (316.861 us; speedup 1.0000x reference)
//
#include <hip/hip_runtime.h>
#include <hip/hip_bf16.h>
#include <stdint.h>

// Problem constants (f32 I/O; bf16 internal compute)
constexpr int Hh = 16, Ll = 1024, Dd = 1024, DHh = 64, CL = 1024, TKV = 2048;
constexpr size_t OUT_ELEMS = 4ull * 1024 * 1024;   // B*L*D = 4,194,304 floats

typedef __attribute__((ext_vector_type(8))) short short8;
typedef __attribute__((ext_vector_type(4))) float floatx4;

#define MFMA16(a, b, c) __builtin_amdgcn_mfma_f32_16x16x32_bf16(a, b, c, 0, 0, 0)

__device__ __forceinline__ short bfs(float x) {
    union { __hip_bfloat16 h; short s; } u;
    u.h = __float2bfloat16(x);
    return u.s;
}

__device__ __forceinline__ short8 cvt8(const float* p) {
    float4 a = *(const float4*)p;
    float4 b = *(const float4*)(p + 4);
    short8 r;
    r[0] = bfs(a.x); r[1] = bfs(a.y); r[2] = bfs(a.z); r[3] = bfs(a.w);
    r[4] = bfs(b.x); r[5] = bfs(b.y); r[6] = bfs(b.z); r[7] = bfs(b.w);
    return r;
}

// ---------------------------------------------------------------------------
// Kernel 1: exact f32 copy of old cache into new_cache[t < CL]
// ---------------------------------------------------------------------------
__global__ __launch_bounds__(256) void copy_cache_kernel(
    const float* __restrict__ cache, float* __restrict__ outc) {
    int c = blockIdx.x * 256 + threadIdx.x;   // 1,048,576 chunks of 8 floats
    int bh  = c >> 14;                        // 16384 chunks per (b,h)
    int rem = c & 16383;
    const float* s = cache + (size_t)c * 8;
    float* d = outc + OUT_ELEMS + (size_t)bh * 262144 + (size_t)rem * 8;
    *(float4*)d       = *(const float4*)s;
    *(float4*)(d + 4) = *(const float4*)(s + 4);
}

// ---------------------------------------------------------------------------
// GEMM: C(4096,1024) = A(4096,1024) @ W(1024,1024)^T + bias
// MODE 0: A = bf16 workspace (attn out), C = f32 d_out[0:OUT_ELEMS]
// MODE 1: A = f32 query, C = bf16 Q workspace (B,H,L,DH)
// MODE 2: A = f32 key,   C = f32 new_cache [b,h,CL+l, 0:64]
// MODE 3: A = f32 value, C = f32 new_cache [b,h,CL+l, 64:128]
// ---------------------------------------------------------------------------
template <int MODE>
__global__ __launch_bounds__(256) void gemm_nt(
    const void* __restrict__ Av, const float* __restrict__ W,
    const float* __restrict__ bias, void* __restrict__ Cv) {
    constexpr int K = 1024, BK = 64;
    __shared__ alignas(16) __hip_bfloat16 As[128 * BK];
    __shared__ alignas(16) __hip_bfloat16 Bs[128 * BK];

    const int tid = threadIdx.x;
    const int w = tid >> 6, lane = tid & 63;
    const int g = lane >> 4, lr = lane & 15;
    const int tm = blockIdx.x * 128, tn = blockIdx.y * 128;
    const int wr = (w >> 1) * 64, wc = (w & 1) * 64;

    floatx4 acc[4][4] = {};

    for (int k0 = 0; k0 < K; k0 += BK) {
        __syncthreads();
#pragma unroll
        for (int i = 0; i < 4; i++) {
            int c = i * 256 + tid;            // 1024 chunks of 8 elems per tile
            int row = c >> 3, colc = (c & 7) * 8;
            if (MODE == 0) {
                const __hip_bfloat16* A = (const __hip_bfloat16*)Av;
                *(short8*)&As[row * BK + colc] =
                    *(const short8*)(A + (size_t)(tm + row) * K + k0 + colc);
            } else {
                const float* A = (const float*)Av;
                *(short8*)&As[row * BK + colc] = cvt8(A + (size_t)(tm + row) * K + k0 + colc);
            }
            *(short8*)&Bs[row * BK + colc] = cvt8(W + (size_t)(tn + row) * K + k0 + colc);
        }
        __syncthreads();
#pragma unroll
        for (int kk = 0; kk < 2; kk++) {
            short8 af[4], bf[4];
#pragma unroll
            for (int i = 0; i < 4; i++)
                af[i] = *(const short8*)&As[(wr + i * 16 + lr) * BK + kk * 32 + g * 8];
#pragma unroll
            for (int j = 0; j < 4; j++)
                bf[j] = *(const short8*)&Bs[(wc + j * 16 + lr) * BK + kk * 32 + g * 8];
#pragma unroll
            for (int i = 0; i < 4; i++)
#pragma unroll
                for (int j = 0; j < 4; j++)
                    acc[i][j] = MFMA16(af[i], bf[j], acc[i][j]);
        }
    }

    // Epilogue: bias + mode-specific scatter (f32 except MODE 1 -> bf16 ws)
#pragma unroll
    for (int j = 0; j < 4; j++) {
        int n = tn + wc + j * 16 + lr;
        float bv = bias[n];
#pragma unroll
        for (int i = 0; i < 4; i++) {
#pragma unroll
            for (int r = 0; r < 4; r++) {
                int m = tm + wr + i * 16 + g * 4 + r;
                float v = acc[i][j][r] + bv;
                if (MODE == 0) {
                    ((float*)Cv)[(size_t)m * 1024 + n] = v;
                } else if (MODE == 1) {
                    size_t addr = (size_t)(m >> 10) * ((size_t)Hh * Ll * DHh) +
                                  (size_t)(n >> 6) * ((size_t)Ll * DHh) +
                                  (size_t)(m & 1023) * DHh + (n & 63);
                    ((__hip_bfloat16*)Cv)[addr] = __float2bfloat16(v);
                } else {
                    size_t bh = (size_t)((m >> 10) * Hh + (n >> 6));
                    size_t addr = OUT_ELEMS + (bh * TKV + CL + (m & 1023)) * 128 + (n & 63) +
                                  (MODE == 3 ? 64 : 0);
                    ((float*)Cv)[addr] = v;
                }
            }
        }
    }
}

// ---------------------------------------------------------------------------
// Flash attention: grid (B*H, L/64), 256 threads = 4 waves, wave owns 16 q-rows.
// Q from bf16 workspace (B,H,L,DH); K/V from f32 new_cache (converted on stage).
// Writes normalized O as bf16 workspace in (B,L,D) layout.
// ---------------------------------------------------------------------------
__global__ __launch_bounds__(256) void attn_kernel(
    const __hip_bfloat16* __restrict__ qws, const float* __restrict__ kv,
    __hip_bfloat16* __restrict__ ows) {
    __shared__ alignas(16) __hip_bfloat16 Ks[64 * 72];
    __shared__ alignas(16) __hip_bfloat16 Vt[64 * 72];
    __shared__ alignas(16) __hip_bfloat16 Ps[4][16 * 72];

    const int tid = threadIdx.x;
    const int w = tid >> 6, lane = tid & 63;
    const int g = lane >> 4, lr = lane & 15;
    const int bh = blockIdx.x;            // b*16 + h
    const int q0 = blockIdx.y * 64 + w * 16;

    const __hip_bfloat16* qbase = qws + (size_t)bh * Ll * DHh;
    const float* kvb = kv + (size_t)bh * TKV * 128;

    short8 qf[2];
#pragma unroll
    for (int kk = 0; kk < 2; kk++)
        qf[kk] = *(const short8*)(qbase + (size_t)(q0 + lr) * DHh + kk * 32 + g * 8);

    float rm[4], rl[4];
    floatx4 o[4] = {};
#pragma unroll
    for (int j = 0; j < 4; j++) { rm[j] = -3e38f; rl[j] = 0.f; }

    for (int t0 = 0; t0 < TKV; t0 += 64) {
        __syncthreads();
        // stage K (row-major, pad 72) and V transposed (Vt[dh][t], pad 72), f32->bf16
#pragma unroll
        for (int it = 0; it < 2; it++) {
            int c = it * 256 + tid;
            int t = c >> 3, off = (c & 7) * 8;
            const float* gp = kvb + (size_t)(t0 + t) * 128;
            *(short8*)&Ks[t * 72 + off] = cvt8(gp + off);
            float4 v0 = *(const float4*)(gp + 64 + off);
            float4 v1 = *(const float4*)(gp + 64 + off + 4);
            float vv[8] = {v0.x, v0.y, v0.z, v0.w, v1.x, v1.y, v1.z, v1.w};
#pragma unroll
            for (int e = 0; e < 8; e++)
                ((short*)Vt)[(off + e) * 72 + t] = bfs(vv[e]);
        }
        __syncthreads();

        // S = (Q @ K^T) / 8
        floatx4 s[4];
#pragma unroll
        for (int f = 0; f < 4; f++) {
            floatx4 z = {};
#pragma unroll
            for (int kk = 0; kk < 2; kk++) {
                short8 bfr = *(const short8*)&Ks[(f * 16 + lr) * 72 + kk * 32 + g * 8];
                z = MFMA16(qf[kk], bfr, z);
            }
            s[f] = z * 0.125f;
        }

        // online softmax: row r = g*4 + j lives on the 16 lanes of group g
        float mt[4];
#pragma unroll
        for (int j = 0; j < 4; j++) {
            float mv = fmaxf(fmaxf(s[0][j], s[1][j]), fmaxf(s[2][j], s[3][j]));
            mv = fmaxf(mv, __shfl_xor(mv, 1));
            mv = fmaxf(mv, __shfl_xor(mv, 2));
            mv = fmaxf(mv, __shfl_xor(mv, 4));
            mv = fmaxf(mv, __shfl_xor(mv, 8));
            mt[j] = mv;
        }
        float corr[4];
#pragma unroll
        for (int j = 0; j < 4; j++) {
            float mn = fmaxf(rm[j], mt[j]);
            corr[j] = __expf(rm[j] - mn);
            rm[j] = mn;
        }
        float rs[4] = {0.f, 0.f, 0.f, 0.f};
#pragma unroll
        for (int f = 0; f < 4; f++)
#pragma unroll
            for (int j = 0; j < 4; j++) {
                float p = __expf(s[f][j] - rm[j]);
                s[f][j] = p;
                rs[j] += p;
            }
#pragma unroll
        for (int j = 0; j < 4; j++) {
            rs[j] += __shfl_xor(rs[j], 1);
            rs[j] += __shfl_xor(rs[j], 2);
            rs[j] += __shfl_xor(rs[j], 4);
            rs[j] += __shfl_xor(rs[j], 8);
            rl[j] = rl[j] * corr[j] + rs[j];
#pragma unroll
            for (int f2 = 0; f2 < 4; f2++) o[f2][j] = o[f2][j] * corr[j];
        }

        // P -> LDS (per-wave region), then PV MFMA
        __hip_bfloat16* pw = &Ps[w][0];
#pragma unroll
        for (int f = 0; f < 4; f++)
#pragma unroll
            for (int j = 0; j < 4; j++)
                pw[(g * 4 + j) * 72 + f * 16 + lr] = __float2bfloat16(s[f][j]);

#pragma unroll
        for (int kk = 0; kk < 2; kk++) {
            short8 pa = *(const short8*)&pw[lr * 72 + kk * 32 + g * 8];
#pragma unroll
            for (int f2 = 0; f2 < 4; f2++) {
                short8 vb = *(const short8*)&Vt[(f2 * 16 + lr) * 72 + kk * 32 + g * 8];
                o[f2] = MFMA16(pa, vb, o[f2]);
            }
        }
    }

    // Epilogue: normalize and store bf16 to (B,L,D) workspace
    const int b = bh >> 4, h = bh & 15;
#pragma unroll
    for (int j = 0; j < 4; j++) {
        float inv = 1.0f / rl[j];
        int qrow = q0 + g * 4 + j;
        size_t rb = ((size_t)b * Ll + qrow) * Dd + (size_t)h * DHh;
#pragma unroll
        for (int f2 = 0; f2 < 4; f2++)
            ows[rb + f2 * 16 + lr] = __float2bfloat16(o[f2][j] * inv);
    }
}

// ---------------------------------------------------------------------------
extern "C" void kernel_launch(void* const* d_in, const int* in_sizes, int n_in,
                              void* d_out, int out_size, void* d_ws, size_t ws_size,
                              hipStream_t stream) {
    (void)in_sizes; (void)n_in; (void)out_size; (void)ws_size;
    const float* query = (const float*)d_in[0];
    const float* key   = (const float*)d_in[1];
    const float* value = (const float*)d_in[2];
    const float* cache = (const float*)d_in[3];
    const float* Wq = (const float*)d_in[4];
    const float* bq = (const float*)d_in[5];
    const float* Wk = (const float*)d_in[6];
    const float* bk = (const float*)d_in[7];
    const float* Wv = (const float*)d_in[8];
    const float* bv = (const float*)d_in[9];
    const float* Wo = (const float*)d_in[10];
    const float* bo = (const float*)d_in[11];

    float* out = (float*)d_out;
    __hip_bfloat16* qws = (__hip_bfloat16*)d_ws;          // (B,H,L,DH) bf16, 8 MB
    __hip_bfloat16* aws = qws + OUT_ELEMS;                // (B,L,D)    bf16, 8 MB

    dim3 bb(256);
    copy_cache_kernel<<<dim3(4096), bb, 0, stream>>>(cache, out);

    dim3 gg(32, 8);
    gemm_nt<1><<<gg, bb, 0, stream>>>(query, Wq, bq, qws);
    gemm_nt<2><<<gg, bb, 0, stream>>>(key, Wk, bk, out);
    gemm_nt<3><<<gg, bb, 0, stream>>>(value, Wv, bv, out);

    attn_kernel<<<dim3(64, 16), bb, 0, stream>>>(qws, out + OUT_ELEMS, aws);

    gemm_nt<0><<<gg, bb, 0, stream>>>(aws, Wo, bo, out);
}